// Round 5
// baseline (24.799 us; speedup 1.0000x reference)
//
#include <hip/hip_runtime.h>
#include <math.h>

#define NB 32
#define NA 3
#define NH 52
#define NW 52
#define NC 80
#define G  20
#define CH 85               // 5 + NC
#define PLANE (NH*NW)       // 2704
#define APLANE (NA*PLANE)   // 8112 cells per batch
#define QUADS_PER_B (APLANE/4)   // 2028 4-cell groups per batch
#define CELL_BLOCKS 256     // 8 blocks/batch * 32 batches
#define PAIR_BLOCKS 160     // 640 pairs, 4 waves/block
#define TOTAL_BLOCKS (CELL_BLOCKS + PAIR_BLOCKS)  // 416
#define NPAIR (NB*G)        // 640
#define CNT_OFF (TOTAL_BLOCKS*8)   // float index of the done-counter in ws

__constant__ float c_aw[NA] = {1.25f, 2.0f, 4.125f};   // ANCHORS_PX / SCALE (SCALE=8)
__constant__ float c_ah[NA] = {1.625f, 3.75f, 2.875f};

__device__ __forceinline__ float rcp_(float x) { return __builtin_amdgcn_rcpf(x); }
__device__ __forceinline__ float sigmoidf_(float x) { return rcp_(1.0f + __expf(-x)); }
__device__ __forceinline__ float softplusf_(float x) {
    return fmaxf(x, 0.0f) + __logf(1.0f + __expf(-fabsf(x)));
}

// ws: 416 rows x 8 floats (block partials), then a 4-byte done-counter.
// fields: 0=conf 1=xc 2=yc 3=w 4=h 5=cls 6=ncorr 7=pad

__global__ void __launch_bounds__(256)
main_kernel(const float* __restrict__ out,
            const float* __restrict__ bboxes,
            const int*   __restrict__ labels,
            const int*   __restrict__ anchor_idx,
            const int*   __restrict__ warm_up,
            float* __restrict__ ws,
            float* __restrict__ o,
            unsigned int* __restrict__ counter)
{
    __shared__ float s_x0[G], s_y0[G], s_x1[G], s_y1[G], s_nag[G];
    __shared__ float red[4][7];
    __shared__ int islast;
    int bid = blockIdx.x;
    int t = threadIdx.x;
    int lane = t & 63, wid = t >> 6;

    if (bid < CELL_BLOCKS) {
        // ================= cell path: 4 cells/thread via float4 =================
        int b_i = bid >> 3;
        int bx  = bid & 7;
        if (t < G) {
            const float* gb = bboxes + ((size_t)b_i * G + t) * 4;
            float gx = gb[0] * 0.125f, gy = gb[1] * 0.125f;
            float gw = gb[2] * 0.125f, gh = gb[3] * 0.125f;
            s_x0[t] = gx - 0.5f * gw;
            s_y0[t] = gy - 0.5f * gh;
            s_x1[t] = gx + 0.5f * gw;
            s_y1[t] = gy + 0.5f * gh;
            s_nag[t] = -(gw * gh);
        }
        __syncthreads();

        bool wu = (*warm_up != 0);
        float sc = 0.f, sx = 0.f, sy = 0.f, sw = 0.f, sh = 0.f;
        int idx4 = bx * 256 + t;
        if (idx4 < QUADS_PER_B) {
            int cell0 = idx4 * 4;
            int a_i = cell0 / PLANE;
            int rem = cell0 - a_i * PLANE;
            int h_i = rem / NW;
            int w0  = rem - h_i * NW;      // multiple of 4, row-aligned

            const float* base = out + ((size_t)b_i * NA * CH + (size_t)a_i * CH) * PLANE
                                    + h_i * NW + w0;
            float4 v0 = *(const float4*)(base);
            float4 v1 = *(const float4*)(base + PLANE);
            float4 v2 = *(const float4*)(base + 2 * PLANE);
            float4 v3 = *(const float4*)(base + 3 * PLANE);
            float4 v4 = *(const float4*)(base + 4 * PLANE);
            float o0[4] = {v0.x, v0.y, v0.z, v0.w};
            float o1[4] = {v1.x, v1.y, v1.z, v1.w};
            float o2[4] = {v2.x, v2.y, v2.z, v2.w};
            float o3[4] = {v3.x, v3.y, v3.z, v3.w};
            float o4[4] = {v4.x, v4.y, v4.z, v4.w};

            float aw = c_aw[a_i], ah = c_ah[a_i];
            float px0[4], py0[4], px1[4], py1[4], apeps[4], xc[4], yc[4], m[4];
            #pragma unroll
            for (int j = 0; j < 4; ++j) {
                xc[j] = sigmoidf_(o0[j]);
                yc[j] = sigmoidf_(o1[j]);
                float pw = __expf(o2[j]) * aw;
                float ph = __expf(o3[j]) * ah;
                float px = xc[j] + (float)(w0 + j), py = yc[j] + (float)h_i;
                px0[j] = px - 0.5f * pw; py0[j] = py - 0.5f * ph;
                px1[j] = px + 0.5f * pw; py1[j] = py + 0.5f * ph;
                apeps[j] = pw * ph + 1e-10f;
                m[j] = -1e30f;
            }
            // divide-free ignore: iou>0.5  <=>  3*inter - ag > ap + 1e-10
            #pragma unroll
            for (int g = 0; g < G; ++g) {
                float gx0 = s_x0[g], gy0 = s_y0[g];
                float gx1 = s_x1[g], gy1 = s_y1[g], nag = s_nag[g];
                #pragma unroll
                for (int j = 0; j < 4; ++j) {
                    float iw = fmaxf(fminf(px1[j], gx1) - fmaxf(px0[j], gx0), 0.f);
                    float ih = fmaxf(fminf(py1[j], gy1) - fmaxf(py0[j], gy0), 0.f);
                    float inter = iw * ih;
                    m[j] = fmaxf(m[j], fmaf(3.0f, inter, nag));
                }
            }
            #pragma unroll
            for (int j = 0; j < 4; ++j) {
                bool ignore = m[j] > apeps[j];
                sc += (ignore ? 0.0f : 0.5f) * softplusf_(o4[j]);
                if (wu) {
                    sx += (xc[j] - 0.5f) * (xc[j] - 0.5f);
                    sy += (yc[j] - 0.5f) * (yc[j] - 0.5f);
                    sw += o2[j] * o2[j];
                    sh += o3[j] * o3[j];
                }
            }
        }
        #pragma unroll
        for (int off = 32; off > 0; off >>= 1) {
            sc += __shfl_down(sc, off);
            sx += __shfl_down(sx, off);
            sy += __shfl_down(sy, off);
            sw += __shfl_down(sw, off);
            sh += __shfl_down(sh, off);
        }
        if (lane == 0) {
            red[wid][0] = sc; red[wid][1] = sx; red[wid][2] = sy;
            red[wid][3] = sw; red[wid][4] = sh;
        }
        __syncthreads();
        if (t == 0) {
            float r0 = 0.f, r1 = 0.f, r2 = 0.f, r3 = 0.f, r4 = 0.f;
            #pragma unroll
            for (int w = 0; w < 4; ++w) {
                r0 += red[w][0]; r1 += red[w][1]; r2 += red[w][2];
                r3 += red[w][3]; r4 += red[w][4];
            }
            float4* dst = (float4*)(ws + (size_t)bid * 8);
            dst[0] = make_float4(r0, r1, r2, r3);
            dst[1] = make_float4(r4, 0.f, 0.f, 0.f);
        }
    } else {
        // ================= pair path: one wave per (b,g) pair =================
        int pb = bid - CELL_BLOCKS;
        int p = pb * 4 + wid;            // < 640 always
        int b = p / G, g = p % G;

        const float* gb = bboxes + (size_t)b * G * 4;

        // per-lane GT data (lanes 0..19)
        float qx = 0.f, qy = 0.f, qw = 0.f, qh = 0.f;
        int aq = -1, qi = 0, qj = 0;
        if (lane < G) {
            const float* q4 = gb + lane * 4;
            qx = q4[0] * 0.125f; qy = q4[1] * 0.125f;
            qw = q4[2] * 0.125f; qh = q4[3] * 0.125f;
            aq = anchor_idx[b * G + lane];
            qi = min(max((int)qx, 0), NW - 1);
            qj = min(max((int)qy, 0), NH - 1);
        }
        // own GT broadcast from lane g
        float gx = __shfl(qx, g), gy = __shfl(qy, g);
        float gw = __shfl(qw, g), gh = __shfl(qh, g);
        int a  = __shfl(aq, g);
        int gi = __shfl(qi, g), gj = __shfl(qj, g);

        const float* cell = out + ((size_t)b * NA * CH + (size_t)a * CH) * PLANE
                                + gj * NW + gi;

        // class BCE loads in lane-parallel (issue early)
        int lab = labels[p];
        float v1 = cell[(size_t)(5 + lane) * PLANE];
        float v2 = (lane < NC - 64) ? cell[(size_t)(69 + lane) * PLANE] : 0.f;
        float s = softplusf_(v1) - ((lane == lab) ? v1 : 0.f);
        if (lane < NC - 64)
            s += softplusf_(v2) - (((64 + lane) == lab) ? v2 : 0.f);

        float o0 = cell[0];
        float o1 = cell[PLANE];
        float o2 = cell[2 * PLANE];
        float o3 = cell[3 * PLANE];
        float o4 = cell[4 * PLANE];

        float xc = sigmoidf_(o0), yc = sigmoidf_(o1);
        float pw = __expf(o2) * c_aw[a];
        float ph = __expf(o3) * c_ah[a];
        float px = xc + (float)gi, py = yc + (float)gj;
        float px0 = px - 0.5f*pw, py0 = py - 0.5f*ph;
        float px1 = px + 0.5f*pw, py1 = py + 0.5f*ph;
        float ap = pw * ph;

        // nCorrect: divide-free iou>0.5
        float ncorr;
        {
            float gx0 = gx - 0.5f*gw, gy0 = gy - 0.5f*gh;
            float gx1 = gx + 0.5f*gw, gy1 = gy + 0.5f*gh;
            float iw = fmaxf(fminf(px1, gx1) - fmaxf(px0, gx0), 0.f);
            float ih = fmaxf(fminf(py1, gy1) - fmaxf(py0, gy0), 0.f);
            float inter = iw * ih;
            ncorr = (3.0f * inter - gw * gh > ap + 1e-10f) ? 1.0f : 0.0f;
        }

        // last-wins dedupe via ballot: lane q collides if later pair hits same cell
        bool coll = (lane < G) && (lane > g) && (aq == a) && (qi == gi) && (qj == gj);
        unsigned long long cmask = __ballot(coll);
        bool active = (cmask == 0ull);

        // ignore: lane-parallel d_q = 3*inter_q - ag_q; max-reduce with class sum
        float d = -1e30f;
        if (lane < G) {
            float qx0 = qx - 0.5f*qw, qy0 = qy - 0.5f*qh;
            float qx1 = qx + 0.5f*qw, qy1 = qy + 0.5f*qh;
            float iw = fmaxf(fminf(px1, qx1) - fmaxf(px0, qx0), 0.f);
            float ih = fmaxf(fminf(py1, qy1) - fmaxf(py0, qy0), 0.f);
            float inter = iw * ih;
            d = 3.0f * inter - qw * qh;
        }
        #pragma unroll
        for (int off = 32; off > 0; off >>= 1) {
            s += __shfl_down(s, off);
            d = fmaxf(d, __shfl_down(d, off));
        }

        if (lane == 0) {
            bool ignore = d > ap + 1e-10f;
            float dconf = 0.f, dxc = 0.f, dyc = 0.f, dw = 0.f, dh = 0.f, dcls = 0.f;
            if (active) {
                float sp4 = softplusf_(o4);
                float base_conf = (ignore ? 0.0f : 0.5f) * sp4;
                dconf = 5.0f * (sp4 - o4) - base_conf;

                float txc = gx - (float)gi;
                float tyc = gy - (float)gj;
                float tw  = __logf(gw / c_aw[a]);
                float th  = __logf(gh / c_ah[a]);
                bool wu = (*warm_up != 0);
                float bx = wu ? (xc - 0.5f) * (xc - 0.5f) : 0.f;
                float by = wu ? (yc - 0.5f) * (yc - 0.5f) : 0.f;
                float bw = wu ? o2 * o2 : 0.f;
                float bh = wu ? o3 * o3 : 0.f;
                dxc = (xc - txc) * (xc - txc) - bx;
                dyc = (yc - tyc) * (yc - tyc) - by;
                dw  = (o2 - tw) * (o2 - tw) - bw;
                dh  = (o3 - th) * (o3 - th) - bh;
                dcls = s;
            }
            red[wid][0] = dconf; red[wid][1] = dxc; red[wid][2] = dyc;
            red[wid][3] = dw;    red[wid][4] = dh;  red[wid][5] = dcls;
            red[wid][6] = ncorr;
        }
        __syncthreads();
        if (t == 0) {
            float r[7];
            #pragma unroll
            for (int k = 0; k < 7; ++k)
                r[k] = red[0][k] + red[1][k] + red[2][k] + red[3][k];
            float4* dst = (float4*)(ws + (size_t)bid * 8);
            dst[0] = make_float4(r[0], r[1], r[2], r[3]);
            dst[1] = make_float4(r[4], r[5], r[6], 0.f);
        }
    }

    // ============== last-block-done fused finalize ==============
    if (t == 0) {
        __threadfence();                       // release: row visible device-wide
        unsigned int old = atomicAdd(counter, 1u);
        islast = (old == TOTAL_BLOCKS - 1) ? 1 : 0;
    }
    __syncthreads();
    if (islast) {
        __threadfence();                       // acquire: see all rows
        float a0=0,a1=0,a2=0,a3=0,a4=0,a5=0,a6=0;
        {
            const float4* r = (const float4*)(ws + (size_t)t * 8);
            float4 lo = r[0], hi = r[1];
            a0 += lo.x; a1 += lo.y; a2 += lo.z; a3 += lo.w;
            a4 += hi.x; a5 += hi.y; a6 += hi.z;
        }
        if (t < TOTAL_BLOCKS - 256) {
            const float4* r = (const float4*)(ws + (size_t)(256 + t) * 8);
            float4 lo = r[0], hi = r[1];
            a0 += lo.x; a1 += lo.y; a2 += lo.z; a3 += lo.w;
            a4 += hi.x; a5 += hi.y; a6 += hi.z;
        }
        #pragma unroll
        for (int off = 32; off > 0; off >>= 1) {
            a0 += __shfl_down(a0, off);
            a1 += __shfl_down(a1, off);
            a2 += __shfl_down(a2, off);
            a3 += __shfl_down(a3, off);
            a4 += __shfl_down(a4, off);
            a5 += __shfl_down(a5, off);
            a6 += __shfl_down(a6, off);
        }
        __syncthreads();   // red[][] reuse is safe after this
        if (lane == 0) {
            red[wid][0]=a0; red[wid][1]=a1; red[wid][2]=a2; red[wid][3]=a3;
            red[wid][4]=a4; red[wid][5]=a5; red[wid][6]=a6;
        }
        __syncthreads();
        if (t == 0) {
            float c0=0,c1=0,c2=0,c3=0,c4=0,c5=0,c6=0;
            #pragma unroll
            for (int w = 0; w < 4; ++w) {
                c0+=red[w][0]; c1+=red[w][1]; c2+=red[w][2]; c3+=red[w][3];
                c4+=red[w][4]; c5+=red[w][5]; c6+=red[w][6];
            }
            const float invB = 1.0f / (float)NB;
            float lxc = c1 * 0.5f * invB;
            float lyc = c2 * 0.5f * invB;
            float lw  = c3 * 0.5f * invB;
            float lh  = c4 * 0.5f * invB;
            float lconf = c0 * invB;
            float lcls  = c5 * invB;
            o[0] = lxc + lyc + lw + lh + lconf + lcls;
            o[1] = (float)NPAIR;      // nGT
            o[2] = c6;                // nCorrect
            o[3] = lxc;
            o[4] = lyc;
            o[5] = lw;
            o[6] = lh;
            o[7] = lconf;
            o[8] = lcls;
        }
    }
}

extern "C" void kernel_launch(void* const* d_in, const int* in_sizes, int n_in,
                              void* d_out, int out_size, void* d_ws, size_t ws_size,
                              hipStream_t stream)
{
    const float* output     = (const float*)d_in[0];
    const float* bboxes     = (const float*)d_in[1];
    const int*   labels     = (const int*)d_in[2];
    const int*   anchor_idx = (const int*)d_in[3];
    const int*   warm_up    = (const int*)d_in[4];
    float* ws   = (float*)d_ws;
    float* outp = (float*)d_out;
    unsigned int* counter = (unsigned int*)(ws + CNT_OFF);

    hipMemsetAsync(counter, 0, sizeof(unsigned int), stream);
    main_kernel<<<TOTAL_BLOCKS, 256, 0, stream>>>(
        output, bboxes, labels, anchor_idx, warm_up, ws, outp, counter);
}

// Round 6
// 19.660 us; speedup vs baseline: 1.2614x; 1.2614x over previous
//
#include <hip/hip_runtime.h>
#include <math.h>

#define NB 32
#define NA 3
#define NH 52
#define NW 52
#define NC 80
#define G  20
#define CH 85               // 5 + NC
#define PLANE (NH*NW)       // 2704
#define APLANE (NA*PLANE)   // 8112 cells per batch
#define QUADS_PER_B (APLANE/4)   // 2028 4-cell groups per batch
#define CELL_BLOCKS 256     // 8 blocks/batch * 32 batches
#define PAIR_BLOCKS 160     // 640 pairs, 4 waves/block
#define TOTAL_BLOCKS (CELL_BLOCKS + PAIR_BLOCKS)  // 416 = 8 * 52
#define NPAIR (NB*G)        // 640

// ws layout (floats), all zeroed by a 1088-byte memset each call:
//   [0 .. 128)    8 accumulator rows x 16 floats (64B apart); cols 0..6 used
//   [128 .. 256)  8 sub-counters (uint), one per 16 floats (64B apart)
//   [256 .. 272)  master counter (uint) + pad
#define ACCF 16
#define NROW 8
#define SUB_OFF   (NROW*ACCF)        // 128
#define MASTER_OFF (SUB_OFF + NROW*16)  // 256
#define WS_ZERO_BYTES ((MASTER_OFF + 16) * 4)  // 1088
#define SUB_QUOTA (TOTAL_BLOCKS / NROW)  // 52

__constant__ float c_aw[NA] = {1.25f, 2.0f, 4.125f};   // ANCHORS_PX / SCALE (SCALE=8)
__constant__ float c_ah[NA] = {1.625f, 3.75f, 2.875f};

__device__ __forceinline__ float rcp_(float x) { return __builtin_amdgcn_rcpf(x); }
__device__ __forceinline__ float sigmoidf_(float x) { return rcp_(1.0f + __expf(-x)); }
__device__ __forceinline__ float softplusf_(float x) {
    return fmaxf(x, 0.0f) + __logf(1.0f + __expf(-fabsf(x)));
}

__global__ void __launch_bounds__(256)
main_kernel(const float* __restrict__ out,
            const float* __restrict__ bboxes,
            const int*   __restrict__ labels,
            const int*   __restrict__ anchor_idx,
            const int*   __restrict__ warm_up,
            float* __restrict__ ws,
            float* __restrict__ o)
{
    __shared__ float s_x0[G], s_y0[G], s_x1[G], s_y1[G], s_nag[G];
    __shared__ float red[4][7];
    __shared__ float fin[NROW * ACCF];
    __shared__ int islast;
    int bid = blockIdx.x;
    int t = threadIdx.x;
    int lane = t & 63, wid = t >> 6;
    bool wu = (*warm_up != 0);

    // fr0..fr6 (valid on t==0 only): conf,xc,yc,w,h,cls,ncorr block partials
    float fr0 = 0.f, fr1 = 0.f, fr2 = 0.f, fr3 = 0.f, fr4 = 0.f, fr5 = 0.f, fr6 = 0.f;

    if (bid < CELL_BLOCKS) {
        // ================= cell path: 4 cells/thread via float4 =================
        int b_i = bid >> 3;
        int bx  = bid & 7;
        if (t < G) {
            const float* gb = bboxes + ((size_t)b_i * G + t) * 4;
            float gx = gb[0] * 0.125f, gy = gb[1] * 0.125f;
            float gw = gb[2] * 0.125f, gh = gb[3] * 0.125f;
            s_x0[t] = gx - 0.5f * gw;
            s_y0[t] = gy - 0.5f * gh;
            s_x1[t] = gx + 0.5f * gw;
            s_y1[t] = gy + 0.5f * gh;
            s_nag[t] = -(gw * gh);
        }
        __syncthreads();

        float sc = 0.f, sx = 0.f, sy = 0.f, sw = 0.f, sh = 0.f;
        int idx4 = bx * 256 + t;
        if (idx4 < QUADS_PER_B) {
            int cell0 = idx4 * 4;
            int a_i = cell0 / PLANE;
            int rem = cell0 - a_i * PLANE;
            int h_i = rem / NW;
            int w0  = rem - h_i * NW;      // multiple of 4, row-aligned

            const float* base = out + ((size_t)b_i * NA * CH + (size_t)a_i * CH) * PLANE
                                    + h_i * NW + w0;
            float4 v0 = *(const float4*)(base);
            float4 v1 = *(const float4*)(base + PLANE);
            float4 v2 = *(const float4*)(base + 2 * PLANE);
            float4 v3 = *(const float4*)(base + 3 * PLANE);
            float4 v4 = *(const float4*)(base + 4 * PLANE);
            float o0[4] = {v0.x, v0.y, v0.z, v0.w};
            float o1[4] = {v1.x, v1.y, v1.z, v1.w};
            float o2[4] = {v2.x, v2.y, v2.z, v2.w};
            float o3[4] = {v3.x, v3.y, v3.z, v3.w};
            float o4[4] = {v4.x, v4.y, v4.z, v4.w};

            float aw = c_aw[a_i], ah = c_ah[a_i];
            float px0[4], py0[4], px1[4], py1[4], apeps[4], xc[4], yc[4], m[4];
            #pragma unroll
            for (int j = 0; j < 4; ++j) {
                xc[j] = sigmoidf_(o0[j]);
                yc[j] = sigmoidf_(o1[j]);
                float pw = __expf(o2[j]) * aw;
                float ph = __expf(o3[j]) * ah;
                float px = xc[j] + (float)(w0 + j), py = yc[j] + (float)h_i;
                px0[j] = px - 0.5f * pw; py0[j] = py - 0.5f * ph;
                px1[j] = px + 0.5f * pw; py1[j] = py + 0.5f * ph;
                apeps[j] = pw * ph + 1e-10f;
                m[j] = -1e30f;
            }
            // divide-free ignore: iou>0.5  <=>  3*inter - ag > ap + 1e-10
            #pragma unroll
            for (int g = 0; g < G; ++g) {
                float gx0 = s_x0[g], gy0 = s_y0[g];
                float gx1 = s_x1[g], gy1 = s_y1[g], nag = s_nag[g];
                #pragma unroll
                for (int j = 0; j < 4; ++j) {
                    float iw = fmaxf(fminf(px1[j], gx1) - fmaxf(px0[j], gx0), 0.f);
                    float ih = fmaxf(fminf(py1[j], gy1) - fmaxf(py0[j], gy0), 0.f);
                    float inter = iw * ih;
                    m[j] = fmaxf(m[j], fmaf(3.0f, inter, nag));
                }
            }
            #pragma unroll
            for (int j = 0; j < 4; ++j) {
                bool ignore = m[j] > apeps[j];
                sc += (ignore ? 0.0f : 0.5f) * softplusf_(o4[j]);
                if (wu) {
                    sx += (xc[j] - 0.5f) * (xc[j] - 0.5f);
                    sy += (yc[j] - 0.5f) * (yc[j] - 0.5f);
                    sw += o2[j] * o2[j];
                    sh += o3[j] * o3[j];
                }
            }
        }
        #pragma unroll
        for (int off = 32; off > 0; off >>= 1) sc += __shfl_down(sc, off);
        if (wu) {
            #pragma unroll
            for (int off = 32; off > 0; off >>= 1) {
                sx += __shfl_down(sx, off);
                sy += __shfl_down(sy, off);
                sw += __shfl_down(sw, off);
                sh += __shfl_down(sh, off);
            }
        }
        if (lane == 0) {
            red[wid][0] = sc; red[wid][1] = sx; red[wid][2] = sy;
            red[wid][3] = sw; red[wid][4] = sh;
        }
        __syncthreads();
        if (t == 0) {
            #pragma unroll
            for (int w = 0; w < 4; ++w) {
                fr0 += red[w][0]; fr1 += red[w][1]; fr2 += red[w][2];
                fr3 += red[w][3]; fr4 += red[w][4];
            }
        }
    } else {
        // ================= pair path: one wave per (b,g) pair =================
        int pb = bid - CELL_BLOCKS;
        int p = pb * 4 + wid;            // < 640 always
        int b = p / G, g = p % G;

        const float* gb = bboxes + (size_t)b * G * 4;

        // per-lane GT data (lanes 0..19)
        float qx = 0.f, qy = 0.f, qw = 0.f, qh = 0.f;
        int aq = -1, qi = 0, qj = 0;
        if (lane < G) {
            const float* q4 = gb + lane * 4;
            qx = q4[0] * 0.125f; qy = q4[1] * 0.125f;
            qw = q4[2] * 0.125f; qh = q4[3] * 0.125f;
            aq = anchor_idx[b * G + lane];
            qi = min(max((int)qx, 0), NW - 1);
            qj = min(max((int)qy, 0), NH - 1);
        }
        // own GT broadcast from lane g
        float gx = __shfl(qx, g), gy = __shfl(qy, g);
        float gw = __shfl(qw, g), gh = __shfl(qh, g);
        int a  = __shfl(aq, g);
        int gi = __shfl(qi, g), gj = __shfl(qj, g);

        const float* cell = out + ((size_t)b * NA * CH + (size_t)a * CH) * PLANE
                                + gj * NW + gi;

        // class BCE loads in lane-parallel (issue early)
        int lab = labels[p];
        float v1 = cell[(size_t)(5 + lane) * PLANE];
        float v2 = (lane < NC - 64) ? cell[(size_t)(69 + lane) * PLANE] : 0.f;
        float s = softplusf_(v1) - ((lane == lab) ? v1 : 0.f);
        if (lane < NC - 64)
            s += softplusf_(v2) - (((64 + lane) == lab) ? v2 : 0.f);

        float o0 = cell[0];
        float o1 = cell[PLANE];
        float o2 = cell[2 * PLANE];
        float o3 = cell[3 * PLANE];
        float o4 = cell[4 * PLANE];

        float xc = sigmoidf_(o0), yc = sigmoidf_(o1);
        float pw = __expf(o2) * c_aw[a];
        float ph = __expf(o3) * c_ah[a];
        float px = xc + (float)gi, py = yc + (float)gj;
        float px0 = px - 0.5f*pw, py0 = py - 0.5f*ph;
        float px1 = px + 0.5f*pw, py1 = py + 0.5f*ph;
        float ap = pw * ph;

        // nCorrect: divide-free iou>0.5
        float ncorr;
        {
            float gx0 = gx - 0.5f*gw, gy0 = gy - 0.5f*gh;
            float gx1 = gx + 0.5f*gw, gy1 = gy + 0.5f*gh;
            float iw = fmaxf(fminf(px1, gx1) - fmaxf(px0, gx0), 0.f);
            float ih = fmaxf(fminf(py1, gy1) - fmaxf(py0, gy0), 0.f);
            float inter = iw * ih;
            ncorr = (3.0f * inter - gw * gh > ap + 1e-10f) ? 1.0f : 0.0f;
        }

        // last-wins dedupe via ballot
        bool coll = (lane < G) && (lane > g) && (aq == a) && (qi == gi) && (qj == gj);
        unsigned long long cmask = __ballot(coll);
        bool active = (cmask == 0ull);

        // ignore: lane-parallel d_q = 3*inter_q - ag_q; max-reduce with class sum
        float d = -1e30f;
        if (lane < G) {
            float qx0 = qx - 0.5f*qw, qy0 = qy - 0.5f*qh;
            float qx1 = qx + 0.5f*qw, qy1 = qy + 0.5f*qh;
            float iw = fmaxf(fminf(px1, qx1) - fmaxf(px0, qx0), 0.f);
            float ih = fmaxf(fminf(py1, qy1) - fmaxf(py0, qy0), 0.f);
            float inter = iw * ih;
            d = 3.0f * inter - qw * qh;
        }
        #pragma unroll
        for (int off = 32; off > 0; off >>= 1) {
            s += __shfl_down(s, off);
            d = fmaxf(d, __shfl_down(d, off));
        }

        if (lane == 0) {
            bool ignore = d > ap + 1e-10f;
            float dconf = 0.f, dxc = 0.f, dyc = 0.f, dw = 0.f, dh = 0.f, dcls = 0.f;
            if (active) {
                float sp4 = softplusf_(o4);
                float base_conf = (ignore ? 0.0f : 0.5f) * sp4;
                dconf = 5.0f * (sp4 - o4) - base_conf;

                float txc = gx - (float)gi;
                float tyc = gy - (float)gj;
                float tw  = __logf(gw / c_aw[a]);
                float th  = __logf(gh / c_ah[a]);
                float bx = wu ? (xc - 0.5f) * (xc - 0.5f) : 0.f;
                float by = wu ? (yc - 0.5f) * (yc - 0.5f) : 0.f;
                float bw = wu ? o2 * o2 : 0.f;
                float bh = wu ? o3 * o3 : 0.f;
                dxc = (xc - txc) * (xc - txc) - bx;
                dyc = (yc - tyc) * (yc - tyc) - by;
                dw  = (o2 - tw) * (o2 - tw) - bw;
                dh  = (o3 - th) * (o3 - th) - bh;
                dcls = s;
            }
            red[wid][0] = dconf; red[wid][1] = dxc; red[wid][2] = dyc;
            red[wid][3] = dw;    red[wid][4] = dh;  red[wid][5] = dcls;
            red[wid][6] = ncorr;
        }
        __syncthreads();
        if (t == 0) {
            #pragma unroll
            for (int w = 0; w < 4; ++w) {
                fr0 += red[w][0]; fr1 += red[w][1]; fr2 += red[w][2];
                fr3 += red[w][3]; fr4 += red[w][4]; fr5 += red[w][5];
                fr6 += red[w][6];
            }
        }
    }

    // ========== atomic-only cross-block combine (no fences, no L2 flush) ==========
    if (t == 0) {
        float* row = ws + (size_t)(bid & 7) * ACCF;
        if (fr0 != 0.f) atomicAdd(row + 0, fr0);
        if (fr1 != 0.f) atomicAdd(row + 1, fr1);
        if (fr2 != 0.f) atomicAdd(row + 2, fr2);
        if (fr3 != 0.f) atomicAdd(row + 3, fr3);
        if (fr4 != 0.f) atomicAdd(row + 4, fr4);
        if (fr5 != 0.f) atomicAdd(row + 5, fr5);
        if (fr6 != 0.f) atomicAdd(row + 6, fr6);
        // ensure partial adds reached the coherent point before counting done
        asm volatile("s_waitcnt vmcnt(0)" ::: "memory");
        unsigned int* sub = (unsigned int*)(ws + SUB_OFF + (size_t)(bid & 7) * 16);
        int last = 0;
        unsigned int so = atomicAdd(sub, 1u);
        if (so == SUB_QUOTA - 1) {
            unsigned int* master = (unsigned int*)(ws + MASTER_OFF);
            unsigned int mo = atomicAdd(master, 1u);
            last = (mo == NROW - 1);
        }
        islast = last;
    }
    __syncthreads();

    if (islast) {
        // coherent-point reads of the accumulators (returning atomics)
        if (t < NROW * ACCF) fin[t] = atomicAdd(ws + t, 0.0f);
        __syncthreads();
        if (t == 0) {
            float c[7];
            #pragma unroll
            for (int k = 0; k < 7; ++k) {
                float sum = 0.f;
                #pragma unroll
                for (int r = 0; r < NROW; ++r) sum += fin[r * ACCF + k];
                c[k] = sum;
            }
            const float invB = 1.0f / (float)NB;
            float lxc = c[1] * 0.5f * invB;
            float lyc = c[2] * 0.5f * invB;
            float lw  = c[3] * 0.5f * invB;
            float lh  = c[4] * 0.5f * invB;
            float lconf = c[0] * invB;
            float lcls  = c[5] * invB;
            o[0] = lxc + lyc + lw + lh + lconf + lcls;
            o[1] = (float)NPAIR;      // nGT
            o[2] = c[6];              // nCorrect
            o[3] = lxc;
            o[4] = lyc;
            o[5] = lw;
            o[6] = lh;
            o[7] = lconf;
            o[8] = lcls;
        }
    }
}

extern "C" void kernel_launch(void* const* d_in, const int* in_sizes, int n_in,
                              void* d_out, int out_size, void* d_ws, size_t ws_size,
                              hipStream_t stream)
{
    const float* output     = (const float*)d_in[0];
    const float* bboxes     = (const float*)d_in[1];
    const int*   labels     = (const int*)d_in[2];
    const int*   anchor_idx = (const int*)d_in[3];
    const int*   warm_up    = (const int*)d_in[4];
    float* ws   = (float*)d_ws;
    float* outp = (float*)d_out;

    hipMemsetAsync(ws, 0, WS_ZERO_BYTES, stream);
    main_kernel<<<TOTAL_BLOCKS, 256, 0, stream>>>(
        output, bboxes, labels, anchor_idx, warm_up, ws, outp);
}

// Round 7
// 11.458 us; speedup vs baseline: 2.1643x; 1.7158x over previous
//
#include <hip/hip_runtime.h>
#include <math.h>

#define NB 32
#define NA 3
#define NH 52
#define NW 52
#define NC 80
#define G  20
#define CH 85               // 5 + NC
#define PLANE (NH*NW)       // 2704
#define APLANE (NA*PLANE)   // 8112 cells per batch
#define QUADS_PER_B (APLANE/4)   // 2028 4-cell groups per batch
#define CELL_BLOCKS 256     // 8 blocks/batch * 32 batches
#define PAIR_BLOCKS 160     // 640 pairs, 4 waves/block
#define TOTAL_BLOCKS (CELL_BLOCKS + PAIR_BLOCKS)  // 416
#define NPAIR (NB*G)        // 640

// ws: 416 rows x 8 floats (plain stores, no atomics anywhere).
// rows [0,256): cell blocks {conf,xc,yc,w,h,0,0,0}
// rows [256,416): pair blocks {conf,xc,yc,w,h,cls,ncorr,0}

__constant__ float c_aw[NA] = {1.25f, 2.0f, 4.125f};   // ANCHORS_PX / SCALE (SCALE=8)
__constant__ float c_ah[NA] = {1.625f, 3.75f, 2.875f};

__device__ __forceinline__ float rcp_(float x) { return __builtin_amdgcn_rcpf(x); }
__device__ __forceinline__ float sigmoidf_(float x) { return rcp_(1.0f + __expf(-x)); }
__device__ __forceinline__ float softplusf_(float x) {
    return fmaxf(x, 0.0f) + __logf(1.0f + __expf(-fabsf(x)));
}

__global__ void __launch_bounds__(256)
main_kernel(const float* __restrict__ out,
            const float* __restrict__ bboxes,
            const int*   __restrict__ labels,
            const int*   __restrict__ anchor_idx,
            const int*   __restrict__ warm_up,
            float* __restrict__ ws)
{
    __shared__ float s_x0[G], s_y0[G], s_x1[G], s_y1[G], s_nag[G];
    __shared__ float red[4][7];
    int bid = blockIdx.x;
    int t = threadIdx.x;
    int lane = t & 63, wid = t >> 6;
    bool wu = (*warm_up != 0);

    if (bid < CELL_BLOCKS) {
        // ================= cell path: 4 cells/thread via float4 =================
        int b_i = bid >> 3;
        int bx  = bid & 7;
        if (t < G) {
            const float* gb = bboxes + ((size_t)b_i * G + t) * 4;
            float gx = gb[0] * 0.125f, gy = gb[1] * 0.125f;
            float gw = gb[2] * 0.125f, gh = gb[3] * 0.125f;
            s_x0[t] = gx - 0.5f * gw;
            s_y0[t] = gy - 0.5f * gh;
            s_x1[t] = gx + 0.5f * gw;
            s_y1[t] = gy + 0.5f * gh;
            s_nag[t] = -(gw * gh);
        }
        __syncthreads();

        float sc = 0.f, sx = 0.f, sy = 0.f, sw = 0.f, sh = 0.f;
        int idx4 = bx * 256 + t;
        if (idx4 < QUADS_PER_B) {
            int cell0 = idx4 * 4;
            int a_i = cell0 / PLANE;
            int rem = cell0 - a_i * PLANE;
            int h_i = rem / NW;
            int w0  = rem - h_i * NW;      // multiple of 4, row-aligned

            const float* base = out + ((size_t)b_i * NA * CH + (size_t)a_i * CH) * PLANE
                                    + h_i * NW + w0;
            float4 v0 = *(const float4*)(base);
            float4 v1 = *(const float4*)(base + PLANE);
            float4 v2 = *(const float4*)(base + 2 * PLANE);
            float4 v3 = *(const float4*)(base + 3 * PLANE);
            float4 v4 = *(const float4*)(base + 4 * PLANE);
            float o0[4] = {v0.x, v0.y, v0.z, v0.w};
            float o1[4] = {v1.x, v1.y, v1.z, v1.w};
            float o2[4] = {v2.x, v2.y, v2.z, v2.w};
            float o3[4] = {v3.x, v3.y, v3.z, v3.w};
            float o4[4] = {v4.x, v4.y, v4.z, v4.w};

            float aw = c_aw[a_i], ah = c_ah[a_i];
            float px0[4], py0[4], px1[4], py1[4], apeps[4], xc[4], yc[4], m[4];
            #pragma unroll
            for (int j = 0; j < 4; ++j) {
                xc[j] = sigmoidf_(o0[j]);
                yc[j] = sigmoidf_(o1[j]);
                float pw = __expf(o2[j]) * aw;
                float ph = __expf(o3[j]) * ah;
                float px = xc[j] + (float)(w0 + j), py = yc[j] + (float)h_i;
                px0[j] = px - 0.5f * pw; py0[j] = py - 0.5f * ph;
                px1[j] = px + 0.5f * pw; py1[j] = py + 0.5f * ph;
                apeps[j] = pw * ph + 1e-10f;
                m[j] = -1e30f;
            }
            // divide-free ignore: iou>0.5  <=>  3*inter - ag > ap + 1e-10
            #pragma unroll
            for (int g = 0; g < G; ++g) {
                float gx0 = s_x0[g], gy0 = s_y0[g];
                float gx1 = s_x1[g], gy1 = s_y1[g], nag = s_nag[g];
                #pragma unroll
                for (int j = 0; j < 4; ++j) {
                    float iw = fmaxf(fminf(px1[j], gx1) - fmaxf(px0[j], gx0), 0.f);
                    float ih = fmaxf(fminf(py1[j], gy1) - fmaxf(py0[j], gy0), 0.f);
                    float inter = iw * ih;
                    m[j] = fmaxf(m[j], fmaf(3.0f, inter, nag));
                }
            }
            #pragma unroll
            for (int j = 0; j < 4; ++j) {
                bool ignore = m[j] > apeps[j];
                sc += (ignore ? 0.0f : 0.5f) * softplusf_(o4[j]);
                if (wu) {
                    sx += (xc[j] - 0.5f) * (xc[j] - 0.5f);
                    sy += (yc[j] - 0.5f) * (yc[j] - 0.5f);
                    sw += o2[j] * o2[j];
                    sh += o3[j] * o3[j];
                }
            }
        }
        #pragma unroll
        for (int off = 32; off > 0; off >>= 1) sc += __shfl_down(sc, off);
        if (wu) {
            #pragma unroll
            for (int off = 32; off > 0; off >>= 1) {
                sx += __shfl_down(sx, off);
                sy += __shfl_down(sy, off);
                sw += __shfl_down(sw, off);
                sh += __shfl_down(sh, off);
            }
        }
        if (lane == 0) {
            red[wid][0] = sc; red[wid][1] = sx; red[wid][2] = sy;
            red[wid][3] = sw; red[wid][4] = sh;
        }
        __syncthreads();
        if (t == 0) {
            float r0 = 0.f, r1 = 0.f, r2 = 0.f, r3 = 0.f, r4 = 0.f;
            #pragma unroll
            for (int w = 0; w < 4; ++w) {
                r0 += red[w][0]; r1 += red[w][1]; r2 += red[w][2];
                r3 += red[w][3]; r4 += red[w][4];
            }
            float4* dst = (float4*)(ws + (size_t)bid * 8);
            dst[0] = make_float4(r0, r1, r2, r3);
            dst[1] = make_float4(r4, 0.f, 0.f, 0.f);
        }
    } else {
        // ================= pair path: one wave per (b,g) pair =================
        int pb = bid - CELL_BLOCKS;
        int p = pb * 4 + wid;            // < 640 always
        int b = p / G, g = p % G;

        const float* gb = bboxes + (size_t)b * G * 4;

        // per-lane GT data (lanes 0..19)
        float qx = 0.f, qy = 0.f, qw = 0.f, qh = 0.f;
        int aq = -1, qi = 0, qj = 0;
        if (lane < G) {
            const float* q4 = gb + lane * 4;
            qx = q4[0] * 0.125f; qy = q4[1] * 0.125f;
            qw = q4[2] * 0.125f; qh = q4[3] * 0.125f;
            aq = anchor_idx[b * G + lane];
            qi = min(max((int)qx, 0), NW - 1);
            qj = min(max((int)qy, 0), NH - 1);
        }
        // own GT broadcast from lane g
        float gx = __shfl(qx, g), gy = __shfl(qy, g);
        float gw = __shfl(qw, g), gh = __shfl(qh, g);
        int a  = __shfl(aq, g);
        int gi = __shfl(qi, g), gj = __shfl(qj, g);

        const float* cell = out + ((size_t)b * NA * CH + (size_t)a * CH) * PLANE
                                + gj * NW + gi;

        // class BCE loads in lane-parallel (issue early)
        int lab = labels[p];
        float v1 = cell[(size_t)(5 + lane) * PLANE];
        float v2 = (lane < NC - 64) ? cell[(size_t)(69 + lane) * PLANE] : 0.f;
        float s = softplusf_(v1) - ((lane == lab) ? v1 : 0.f);
        if (lane < NC - 64)
            s += softplusf_(v2) - (((64 + lane) == lab) ? v2 : 0.f);

        float o0 = cell[0];
        float o1 = cell[PLANE];
        float o2 = cell[2 * PLANE];
        float o3 = cell[3 * PLANE];
        float o4 = cell[4 * PLANE];

        float xc = sigmoidf_(o0), yc = sigmoidf_(o1);
        float pw = __expf(o2) * c_aw[a];
        float ph = __expf(o3) * c_ah[a];
        float px = xc + (float)gi, py = yc + (float)gj;
        float px0 = px - 0.5f*pw, py0 = py - 0.5f*ph;
        float px1 = px + 0.5f*pw, py1 = py + 0.5f*ph;
        float ap = pw * ph;

        // nCorrect: divide-free iou>0.5
        float ncorr;
        {
            float gx0 = gx - 0.5f*gw, gy0 = gy - 0.5f*gh;
            float gx1 = gx + 0.5f*gw, gy1 = gy + 0.5f*gh;
            float iw = fmaxf(fminf(px1, gx1) - fmaxf(px0, gx0), 0.f);
            float ih = fmaxf(fminf(py1, gy1) - fmaxf(py0, gy0), 0.f);
            float inter = iw * ih;
            ncorr = (3.0f * inter - gw * gh > ap + 1e-10f) ? 1.0f : 0.0f;
        }

        // last-wins dedupe via ballot: any later pair hitting same (a,gj,gi)?
        bool coll = (lane < G) && (lane > g) && (aq == a) && (qi == gi) && (qj == gj);
        unsigned long long cmask = __ballot(coll);
        bool active = (cmask == 0ull);

        // ignore: lane-parallel d_q = 3*inter_q - ag_q; max-reduce jointly with s
        float d = -1e30f;
        if (lane < G) {
            float qx0 = qx - 0.5f*qw, qy0 = qy - 0.5f*qh;
            float qx1 = qx + 0.5f*qw, qy1 = qy + 0.5f*qh;
            float iw = fmaxf(fminf(px1, qx1) - fmaxf(px0, qx0), 0.f);
            float ih = fmaxf(fminf(py1, qy1) - fmaxf(py0, qy0), 0.f);
            float inter = iw * ih;
            d = 3.0f * inter - qw * qh;
        }
        #pragma unroll
        for (int off = 32; off > 0; off >>= 1) {
            s += __shfl_down(s, off);
            d = fmaxf(d, __shfl_down(d, off));
        }

        if (lane == 0) {
            bool ignore = d > ap + 1e-10f;
            float dconf = 0.f, dxc = 0.f, dyc = 0.f, dw = 0.f, dh = 0.f, dcls = 0.f;
            if (active) {
                float sp4 = softplusf_(o4);
                float base_conf = (ignore ? 0.0f : 0.5f) * sp4;
                dconf = 5.0f * (sp4 - o4) - base_conf;

                float txc = gx - (float)gi;
                float tyc = gy - (float)gj;
                float tw  = __logf(gw / c_aw[a]);
                float th  = __logf(gh / c_ah[a]);
                float bx = wu ? (xc - 0.5f) * (xc - 0.5f) : 0.f;
                float by = wu ? (yc - 0.5f) * (yc - 0.5f) : 0.f;
                float bw = wu ? o2 * o2 : 0.f;
                float bh = wu ? o3 * o3 : 0.f;
                dxc = (xc - txc) * (xc - txc) - bx;
                dyc = (yc - tyc) * (yc - tyc) - by;
                dw  = (o2 - tw) * (o2 - tw) - bw;
                dh  = (o3 - th) * (o3 - th) - bh;
                dcls = s;
            }
            red[wid][0] = dconf; red[wid][1] = dxc; red[wid][2] = dyc;
            red[wid][3] = dw;    red[wid][4] = dh;  red[wid][5] = dcls;
            red[wid][6] = ncorr;
        }
        __syncthreads();
        if (t == 0) {
            float r[7];
            #pragma unroll
            for (int k = 0; k < 7; ++k)
                r[k] = red[0][k] + red[1][k] + red[2][k] + red[3][k];
            float4* dst = (float4*)(ws + (size_t)bid * 8);
            dst[0] = make_float4(r[0], r[1], r[2], r[3]);
            dst[1] = make_float4(r[4], r[5], r[6], 0.f);
        }
    }
}

__global__ void __launch_bounds__(256)
finalize_kernel(const float* __restrict__ ws, float* __restrict__ o)
{
    __shared__ float red[4][7];
    int t = threadIdx.x;
    float a0=0,a1=0,a2=0,a3=0,a4=0,a5=0,a6=0;

    {
        const float4* r = (const float4*)(ws + (size_t)t * 8);
        float4 lo = r[0], hi = r[1];
        a0 += lo.x; a1 += lo.y; a2 += lo.z; a3 += lo.w;
        a4 += hi.x; a5 += hi.y; a6 += hi.z;
    }
    if (t < TOTAL_BLOCKS - 256) {
        const float4* r = (const float4*)(ws + (size_t)(256 + t) * 8);
        float4 lo = r[0], hi = r[1];
        a0 += lo.x; a1 += lo.y; a2 += lo.z; a3 += lo.w;
        a4 += hi.x; a5 += hi.y; a6 += hi.z;
    }
    #pragma unroll
    for (int off = 32; off > 0; off >>= 1) {
        a0 += __shfl_down(a0, off);
        a1 += __shfl_down(a1, off);
        a2 += __shfl_down(a2, off);
        a3 += __shfl_down(a3, off);
        a4 += __shfl_down(a4, off);
        a5 += __shfl_down(a5, off);
        a6 += __shfl_down(a6, off);
    }
    int lane = t & 63, wid = t >> 6;
    if (lane == 0) {
        red[wid][0]=a0; red[wid][1]=a1; red[wid][2]=a2; red[wid][3]=a3;
        red[wid][4]=a4; red[wid][5]=a5; red[wid][6]=a6;
    }
    __syncthreads();
    if (t == 0) {
        float c0=0,c1=0,c2=0,c3=0,c4=0,c5=0,c6=0;
        #pragma unroll
        for (int w = 0; w < 4; ++w) {
            c0+=red[w][0]; c1+=red[w][1]; c2+=red[w][2]; c3+=red[w][3];
            c4+=red[w][4]; c5+=red[w][5]; c6+=red[w][6];
        }
        const float invB = 1.0f / (float)NB;
        float lxc = c1 * 0.5f * invB;
        float lyc = c2 * 0.5f * invB;
        float lw  = c3 * 0.5f * invB;
        float lh  = c4 * 0.5f * invB;
        float lconf = c0 * invB;
        float lcls  = c5 * invB;
        o[0] = lxc + lyc + lw + lh + lconf + lcls;
        o[1] = (float)NPAIR;      // nGT
        o[2] = c6;                // nCorrect
        o[3] = lxc;
        o[4] = lyc;
        o[5] = lw;
        o[6] = lh;
        o[7] = lconf;
        o[8] = lcls;
    }
}

extern "C" void kernel_launch(void* const* d_in, const int* in_sizes, int n_in,
                              void* d_out, int out_size, void* d_ws, size_t ws_size,
                              hipStream_t stream)
{
    const float* output     = (const float*)d_in[0];
    const float* bboxes     = (const float*)d_in[1];
    const int*   labels     = (const int*)d_in[2];
    const int*   anchor_idx = (const int*)d_in[3];
    const int*   warm_up    = (const int*)d_in[4];
    float* ws   = (float*)d_ws;
    float* outp = (float*)d_out;

    main_kernel<<<TOTAL_BLOCKS, 256, 0, stream>>>(
        output, bboxes, labels, anchor_idx, warm_up, ws);
    finalize_kernel<<<1, 256, 0, stream>>>(ws, outp);
}